// Round 4
// baseline (1277.902 us; speedup 1.0000x reference)
//
#include <hip/hip_runtime.h>
#include <math.h>

#define KZ   20
#define IFZ  128
#define AHZ  4
#define AFZ  32
#define NKV  80            // KZ*AHZ
#define NPB  4             // batch elements per block
#define ROWS 80            // NPB*KZ  (= 5 M-tiles of 16, exact)
#define THREADS 512
#define INV_SCALE 0.1767766952966369f   // 1/sqrt(32)

// packed-weight column layout (592 cols, 37 tiles of 16):
//   [0,128):Wq  [128,256):Wk  [256,336):Wb  [336,464):Wv  [464,592):Wg
// tiles: q:0-7  k:8-15  b:16-20  v:21-28  g:29-36 ; Wo: tiles 37-44
#define NT_ALL 45
#define WPACK_ELEMS (NT_ALL*4*512)      // 92160 bf16 per component

// ---- LDS layout (147.5 KB, 1 block/CU) --------------------------------
// region A: [0,40960)      y hi/lo bf16 (phases 1-4) -> attnout hi/lo (5+)
// region B: [40960,83200)  x fp32 staging -> q fp32 [80][QS] -> v fp32
// region C: [83200,125440) k fp32 [80][QS] -> g fp32
// region D: [125440,151040) bias/w fp32 [80][80]
#define YHI_OFF 0
#define YLO_OFF 20480
#define AHI_OFF 0
#define ALO_OFF 20480
#define X_OFF   40960
#define Q_OFF   40960
#define V_OFF   40960
#define K_OFF   83200
#define G_OFF   83200
#define B_OFF   125440
#define SMEM_BYTES 151040
#define QS 132             // fp32 row stride for q/k/v/g (16B-aligned)

typedef __attribute__((ext_vector_type(8))) short short8;
typedef __attribute__((ext_vector_type(4))) float f32x4;

__device__ __forceinline__ unsigned short f2bf(float f) {
    unsigned int u = __float_as_uint(f);
    unsigned int r = (u + 0x7FFFu + ((u >> 16) & 1u)) >> 16;   // RNE
    return (unsigned short)r;
}
__device__ __forceinline__ float bf2f(unsigned short h) {
    return __uint_as_float(((unsigned int)h) << 16);
}

// ---- prep: pack all weights as bf16 hi/lo fragment blocks --------------
// frag block (tile c, k-step s): 64 lanes x 8 elems; lane l, slot j holds
// W[s*32 + 8*(l>>4) + j][c*16 + (l&15)]  -> one coalesced 1KB load/frag.
__global__ void prep_weights(const float* __restrict__ Wq, const float* __restrict__ Wk,
                             const float* __restrict__ Wv, const float* __restrict__ Wb,
                             const float* __restrict__ Wg, const float* __restrict__ Wo,
                             unsigned short* __restrict__ whi, unsigned short* __restrict__ wlo)
{
    const int fb = blockIdx.x;            // tile*4 + s, 0..179
    const int c = fb >> 2, s = fb & 3;
    const int t = threadIdx.x;            // 0..511
    const int lane = t >> 3, j = t & 7;
    const int k = s*32 + ((lane >> 4) << 3) + j;
    const int col16 = lane & 15;
    float w;
    if (c < 37) {
        int pc = c*16 + col16;
        if      (pc < 128) w = Wq[k*128 + pc];
        else if (pc < 256) w = Wk[k*128 + pc - 128];
        else if (pc < 336) w = Wb[k*80  + pc - 256];
        else if (pc < 464) w = Wv[k*128 + pc - 336];
        else               w = Wg[k*128 + pc - 464];
    } else {
        w = Wo[k*128 + (c - 37)*16 + col16];
    }
    unsigned short hb = f2bf(w);
    unsigned short lb = f2bf(w - bf2f(hb));
    int idx = fb*512 + t;
    whi[idx] = hb;
    wlo[idx] = lb;
}

// ---- NC output tiles sharing one A-fragment sweep (K=128, hi/lo) -------
template<int NC>
__device__ __forceinline__ void gemm_tiles(const unsigned char* smem,
                                           int ahi_off, int alo_off,
                                           const unsigned short* __restrict__ whi,
                                           const unsigned short* __restrict__ wlo,
                                           int c0, int lane, f32x4 (&acc)[NC][5])
{
    const int g = lane >> 4, r = lane & 15;
    #pragma unroll
    for (int nc = 0; nc < NC; ++nc)
        #pragma unroll
        for (int m = 0; m < 5; ++m) acc[nc][m] = (f32x4){0.f, 0.f, 0.f, 0.f};
    #pragma unroll
    for (int s = 0; s < 4; ++s) {
        short8 bhi[NC], blo[NC];
        #pragma unroll
        for (int nc = 0; nc < NC; ++nc) {
            bhi[nc] = *(const short8*)(whi + (size_t)((c0 + nc)*4 + s)*512 + lane*8);
            blo[nc] = *(const short8*)(wlo + (size_t)((c0 + nc)*4 + s)*512 + lane*8);
        }
        #pragma unroll
        for (int m = 0; m < 5; ++m) {
            int row = m*16 + r;
            int cb  = (s*64 + g*16) ^ ((row & 7) << 4);   // XOR-swizzle
            short8 ahi = *(const short8*)(smem + ahi_off + row*256 + cb);
            short8 alo = *(const short8*)(smem + alo_off + row*256 + cb);
            #pragma unroll
            for (int nc = 0; nc < NC; ++nc) {
                acc[nc][m] = __builtin_amdgcn_mfma_f32_16x16x32_bf16(ahi, bhi[nc], acc[nc][m], 0, 0, 0);
                acc[nc][m] = __builtin_amdgcn_mfma_f32_16x16x32_bf16(ahi, blo[nc], acc[nc][m], 0, 0, 0);
                acc[nc][m] = __builtin_amdgcn_mfma_f32_16x16x32_bf16(alo, bhi[nc], acc[nc][m], 0, 0, 0);
            }
        }
    }
}

__global__ __launch_bounds__(512, 2)
void tri_main(const float* __restrict__ x,
              const float* __restrict__ ls, const float* __restrict__ lbv,
              const float* __restrict__ bgv, const float* __restrict__ bov,
              const unsigned short* __restrict__ whi,
              const unsigned short* __restrict__ wlo,
              float* __restrict__ out)
{
    __shared__ unsigned char smem[SMEM_BYTES];
    const int t = threadIdx.x;
    const int wave = t >> 6, lane = t & 63;
    const int b = blockIdx.x;
    const float* xn = x + (size_t)b * (ROWS*IFZ);

    float* s_x   = (float*)(smem + X_OFF);
    float* qf    = (float*)(smem + Q_OFF);
    float* kf    = (float*)(smem + K_OFF);
    float* vf    = (float*)(smem + V_OFF);
    float* gf    = (float*)(smem + G_OFF);
    float* biasf = (float*)(smem + B_OFF);

    // ---- 0: stage x ----------------------------------------------------
    {
        const float4* gx = (const float4*)xn;
        float4* sx = (float4*)s_x;
        #pragma unroll
        for (int i = 0; i < 5; ++i) sx[t + i*512] = gx[t + i*512];
    }
    __syncthreads();

    // ---- 1: LayerNorm -> y hi/lo (swizzled bf16) -----------------------
    {
        const float ls0 = ls[lane], ls1 = ls[lane + 64];
        const float lb0 = lbv[lane], lb1 = lbv[lane + 64];
        for (int rr = 0; rr < 10; ++rr) {
            int row = wave + rr*8;
            float a0 = s_x[row*128 + lane];
            float a1 = s_x[row*128 + lane + 64];
            float s = a0 + a1, ss = a0*a0 + a1*a1;
            #pragma unroll
            for (int off = 32; off > 0; off >>= 1) {
                s  += __shfl_xor(s,  off);
                ss += __shfl_xor(ss, off);
            }
            float mu   = s * (1.0f/IFZ);
            float var  = ss * (1.0f/IFZ) - mu*mu;
            float rstd = rsqrtf(var + 1e-5f);
            float y0 = (a0 - mu)*rstd*ls0 + lb0;
            float y1 = (a1 - mu)*rstd*ls1 + lb1;
            int xr = (row & 7) << 4;
            unsigned short h0 = f2bf(y0);
            unsigned short h1 = f2bf(y1);
            *(unsigned short*)(smem + YHI_OFF + row*256 + ((lane*2)       ^ xr)) = h0;
            *(unsigned short*)(smem + YHI_OFF + row*256 + (((lane+64)*2)  ^ xr)) = h1;
            *(unsigned short*)(smem + YLO_OFF + row*256 + ((lane*2)       ^ xr)) = f2bf(y0 - bf2f(h0));
            *(unsigned short*)(smem + YLO_OFF + row*256 + (((lane+64)*2)  ^ xr)) = f2bf(y1 - bf2f(h1));
        }
    }
    __syncthreads();

    // ---- 2: GEMM1 pass A -> q, k, bias (tiles 0..20) -------------------
    {
        const int r = lane & 15, g4 = (lane >> 4) * 4;
        auto store_qkb = [&](int ci, const f32x4 (&a5)[5]) {
            const int col = ci*16 + r;
            if (ci < 8) {
                #pragma unroll
                for (int m = 0; m < 5; ++m)
                    #pragma unroll
                    for (int p = 0; p < 4; ++p)
                        qf[(m*16 + g4 + p)*QS + col] = a5[m][p];
            } else if (ci < 16) {
                #pragma unroll
                for (int m = 0; m < 5; ++m)
                    #pragma unroll
                    for (int p = 0; p < 4; ++p)
                        kf[(m*16 + g4 + p)*QS + (col - 128)] = a5[m][p];
            } else {
                #pragma unroll
                for (int m = 0; m < 5; ++m)
                    #pragma unroll
                    for (int p = 0; p < 4; ++p)
                        biasf[(m*16 + g4 + p)*NKV + (col - 256)] = a5[m][p];
            }
        };
        if (wave < 5) {
            f32x4 acc[3][5];
            const int c0 = wave*3;
            gemm_tiles<3>(smem, YHI_OFF, YLO_OFF, whi, wlo, c0, lane, acc);
            store_qkb(c0,   acc[0]);
            store_qkb(c0+1, acc[1]);
            store_qkb(c0+2, acc[2]);
        } else {
            f32x4 acc[2][5];
            const int c0 = 15 + (wave - 5)*2;
            gemm_tiles<2>(smem, YHI_OFF, YLO_OFF, whi, wlo, c0, lane, acc);
            store_qkb(c0,   acc[0]);
            store_qkb(c0+1, acc[1]);
        }
    }
    __syncthreads();

    // ---- 3: scores + softmax, q cached in registers --------------------
    if (t < ROWS*AHZ) {
        const int rn = t >> 2, a = t & 3, n20 = (rn/20)*20;
        f32x4 q[8];
        #pragma unroll
        for (int c4 = 0; c4 < 8; ++c4)
            q[c4] = *(const f32x4*)(qf + rn*QS + a*AFZ + c4*4);
        float sc[KZ];
        #pragma unroll
        for (int j = 0; j < KZ; ++j) {
            const float* kr = kf + (n20 + j)*QS + a*AFZ;
            float d = 0.f;
            #pragma unroll
            for (int c4 = 0; c4 < 8; ++c4) {
                f32x4 kv = *(const f32x4*)(kr + c4*4);
                d = fmaf(q[c4][0], kv[0], d);
                d = fmaf(q[c4][1], kv[1], d);
                d = fmaf(q[c4][2], kv[2], d);
                d = fmaf(q[c4][3], kv[3], d);
            }
            sc[j] = d * INV_SCALE + biasf[rn*NKV + j*AHZ + a];
        }
        float mx = sc[0];
        #pragma unroll
        for (int j = 1; j < KZ; ++j) mx = fmaxf(mx, sc[j]);
        float ssum = 0.f;
        #pragma unroll
        for (int j = 0; j < KZ; ++j) { sc[j] = expf(sc[j] - mx); ssum += sc[j]; }
        float inv = 1.0f / ssum;
        #pragma unroll
        for (int j = 0; j < KZ; ++j) biasf[rn*NKV + j*AHZ + a] = sc[j] * inv;
    }
    __syncthreads();

    // ---- 4: GEMM1 pass B -> v, g (tiles 21..36; overwrites q/k) --------
    {
        const int r = lane & 15, g4 = (lane >> 4) * 4;
        f32x4 acc[2][5];
        const int c0 = 21 + wave*2;
        gemm_tiles<2>(smem, YHI_OFF, YLO_OFF, whi, wlo, c0, lane, acc);
        #pragma unroll
        for (int nc = 0; nc < 2; ++nc) {
            const int ci = c0 + nc;
            const int col = ci*16 + r;
            if (ci < 29) {
                #pragma unroll
                for (int m = 0; m < 5; ++m)
                    #pragma unroll
                    for (int p = 0; p < 4; ++p)
                        vf[(m*16 + g4 + p)*QS + (col - 336)] = acc[nc][m][p];
            } else {
                const float bgc = bgv[col - 464];
                #pragma unroll
                for (int m = 0; m < 5; ++m)
                    #pragma unroll
                    for (int p = 0; p < 4; ++p)
                        gf[(m*16 + g4 + p)*QS + (col - 464)] =
                            1.0f / (1.0f + expf(-(acc[nc][m][p] + bgc)));
            }
        }
    }
    __syncthreads();

    // ---- 5: attnout = gate*(w@v) -> bf16 hi/lo fragments (over y) ------
    if (t < ROWS*AHZ) {
        const int rn = t >> 2, a = t & 3, n20 = (rn/20)*20;
        f32x4 acc[8];
        #pragma unroll
        for (int c4 = 0; c4 < 8; ++c4) acc[c4] = (f32x4){0.f, 0.f, 0.f, 0.f};
        #pragma unroll
        for (int j = 0; j < KZ; ++j) {
            float w = biasf[rn*NKV + j*AHZ + a];
            const float* vr = vf + (n20 + j)*QS + a*AFZ;
            #pragma unroll
            for (int c4 = 0; c4 < 8; ++c4) {
                f32x4 vv = *(const f32x4*)(vr + c4*4);
                acc[c4][0] = fmaf(w, vv[0], acc[c4][0]);
                acc[c4][1] = fmaf(w, vv[1], acc[c4][1]);
                acc[c4][2] = fmaf(w, vv[2], acc[c4][2]);
                acc[c4][3] = fmaf(w, vv[3], acc[c4][3]);
            }
        }
        const int xr = (rn & 7) << 4;
        #pragma unroll
        for (int c4 = 0; c4 < 8; ++c4) {
            f32x4 gg = *(const f32x4*)(gf + rn*QS + a*AFZ + c4*4);
            float o0 = acc[c4][0]*gg[0], o1 = acc[c4][1]*gg[1];
            float o2 = acc[c4][2]*gg[2], o3 = acc[c4][3]*gg[3];
            unsigned short h0 = f2bf(o0), h1 = f2bf(o1), h2 = f2bf(o2), h3 = f2bf(o3);
            uint2 hi, lo;
            hi.x = (unsigned int)h0 | ((unsigned int)h1 << 16);
            hi.y = (unsigned int)h2 | ((unsigned int)h3 << 16);
            lo.x = (unsigned int)f2bf(o0 - bf2f(h0)) | ((unsigned int)f2bf(o1 - bf2f(h1)) << 16);
            lo.y = (unsigned int)f2bf(o2 - bf2f(h2)) | ((unsigned int)f2bf(o3 - bf2f(h3)) << 16);
            int o = a*64 + c4*8;            // byte offset in 256B row (8-aligned)
            *(uint2*)(smem + AHI_OFF + rn*256 + (o ^ xr)) = hi;
            *(uint2*)(smem + ALO_OFF + rn*256 + (o ^ xr)) = lo;
        }
    }
    __syncthreads();

    // ---- 6: GEMM2 (attnout @ Wo) + bo + x residual ---------------------
    {
        f32x4 acc[1][5];
        const int ci = 37 + wave;
        gemm_tiles<1>(smem, AHI_OFF, ALO_OFF, whi, wlo, ci, lane, acc);
        const int col = (ci - 37)*16 + (lane & 15);
        const int g4  = (lane >> 4) * 4;
        const float boc = bov[col];
        float* on = out + (size_t)b * (ROWS*IFZ);
        #pragma unroll
        for (int m = 0; m < 5; ++m)
            #pragma unroll
            for (int p = 0; p < 4; ++p) {
                int row = m*16 + g4 + p;
                on[row*128 + col] = acc[0][m][p] + boc + xn[row*128 + col];
            }
    }
}

extern "C" void kernel_launch(void* const* d_in, const int* in_sizes, int n_in,
                              void* d_out, int out_size, void* d_ws, size_t ws_size,
                              hipStream_t stream) {
    (void)in_sizes; (void)n_in; (void)ws_size; (void)out_size;
    const float* x  = (const float*)d_in[0];
    const float* ls = (const float*)d_in[1];
    const float* lb = (const float*)d_in[2];
    const float* Wq = (const float*)d_in[3];
    const float* Wk = (const float*)d_in[4];
    const float* Wv = (const float*)d_in[5];
    const float* Wb = (const float*)d_in[6];
    const float* Wg = (const float*)d_in[7];
    const float* bg = (const float*)d_in[8];
    const float* Wo = (const float*)d_in[9];
    const float* bo = (const float*)d_in[10];
    float* o = (float*)d_out;

    unsigned short* whi = (unsigned short*)d_ws;
    unsigned short* wlo = whi + WPACK_ELEMS;

    hipLaunchKernelGGL(prep_weights, dim3(NT_ALL*4), dim3(THREADS), 0, stream,
                       Wq, Wk, Wv, Wb, Wg, Wo, whi, wlo);
    hipLaunchKernelGGL(tri_main, dim3(32768/NPB), dim3(THREADS), 0, stream,
                       x, ls, lb, bg, bo, whi, wlo, o);
}